// Round 4
// baseline (3217.164 us; speedup 1.0000x reference)
//
#include <hip/hip_runtime.h>
#include <math.h>

#define NX 192
#define NY 192
#define NZ 96
#define NV 4
#define VOL (NZ * NY * NX)      /* 3,538,944 */
#define NTOT (NV * VOL)         /* 14,155,776 */
#define VOL4 (VOL / 4)
#define NTOT4 (NTOT / 4)
#define YS NX
#define ZS (NY * NX)

#define TX 48                    /* x tile (12 float4 groups) */
#define TY 16                    /* y tile */
#define ZCH 24                   /* z planes per chunk (4 chunks) */
#define NG 14                    /* x groups incl halo: cells [-4, TX+4) */
#define NGP 15                   /* padded row stride (breaks bank conflicts) */
#define AROWS (TY + 4)           /* single-kernel A rows */
#define EROWS (TY + 2)
#define AJOBS (AROWS * NG)       /* 280 */
#define EJOBS (EROWS * NG)       /* 252 */
#define UJOBS (TY * (TX / 4))    /* 192 */

__device__ __forceinline__ float4 min4(float4 a, float4 b) {
    return make_float4(fminf(a.x, b.x), fminf(a.y, b.y),
                       fminf(a.z, b.z), fminf(a.w, b.w));
}
__device__ __forceinline__ float4 max4(float4 a, float4 b) {
    return make_float4(fmaxf(a.x, b.x), fmaxf(a.y, b.y),
                       fmaxf(a.z, b.z), fmaxf(a.w, b.w));
}
// window-3 max over cells [a, b.x..b.w, c] producing max of each 3-window
__device__ __forceinline__ float4 win3max(float a, float4 b, float c) {
    return make_float4(fmaxf(fmaxf(a, b.x), b.y),
                       fmaxf(fmaxf(b.x, b.y), b.z),
                       fmaxf(fmaxf(b.y, b.z), b.w),
                       fmaxf(fmaxf(b.z, b.w), c));
}

__global__ void extract_kernel(const float* __restrict__ pred,
                               const float* __restrict__ target,
                               float* __restrict__ cur) {
    int i = blockIdx.x * blockDim.x + threadIdx.x;
    if (i >= NTOT4) return;
    int v = i / VOL4;
    int p = i - v * VOL4;
    int b = v & 1;
    const float4* src = (const float4*)((v < 2) ? pred : target);
    ((float4*)cur)[i] = src[(size_t)(b * 2 + 1) * VOL4 + p];
}

// ---------------- single-round kernel (round 0) — verified in round 3 -------
__global__ __launch_bounds__(256, 3) void fused_kernel(const float* __restrict__ A,
                                                       float* __restrict__ E,
                                                       float* __restrict__ skel) {
    __shared__ float4 As[4][AROWS][NG];
    __shared__ float4 Es[3][EROWS][NG];
    __shared__ float4 Ms[EROWS][NG];

    const int tid = threadIdx.x;
    const int x0 = blockIdx.x * TX;
    const int y0 = blockIdx.y * TY;
    const int v  = blockIdx.z >> 2;
    const int z0 = (blockIdx.z & 3) * ZCH;
    const int z1 = z0 + ZCH;

    const float* Av = A + (size_t)v * VOL;
    float* Ev = E + (size_t)v * VOL;
    float* Sv = skel + (size_t)v * VOL;

    const float4 PINF4 = make_float4(INFINITY, INFINITY, INFINITY, INFINITY);
    const float4 NINF4 = make_float4(-INFINITY, -INFINITY, -INFINITY, -INFINITY);

    auto stageA = [&](int z) {
        int slot = (z + 8) & 3;
        float4* dst = &As[slot][0][0];
        if (z < 0 || z >= NZ) {
            for (int j = tid; j < AJOBS; j += 256) dst[j] = PINF4;
        } else {
            const float* P = Av + (size_t)z * ZS;
            for (int j = tid; j < AJOBS; j += 256) {
                int r = j / NG, g = j - r * NG;
                int gy = y0 - 2 + r;
                int gx0 = x0 - 4 + 4 * g;
                float4 val = PINF4;
                if (gy >= 0 && gy < NY && gx0 >= 0 && gx0 < NX)
                    val = *(const float4*)(P + gy * YS + gx0);
                dst[j] = val;
            }
        }
    };

    auto eplane = [&](int z) {
        int es = (z + 9) % 3;
        float4* dst = &Es[es][0][0];
        if (z < 0 || z >= NZ) {
            for (int j = tid; j < EJOBS; j += 256) dst[j] = NINF4;
            return;
        }
        const int sc = (z + 8) & 3;
        const int sm = (z + 7) & 3;
        const int sp = (z + 9) & 3;
        const bool wr = (z >= z0 && z < z1);
        for (int j = tid; j < EJOBS; j += 256) {
            int r = j / NG, g = j - r * NG;
            float4 c  = As[sc][r + 1][g];
            float4 yl = As[sc][r][g];
            float4 yh = As[sc][r + 2][g];
            float4 zl = As[sm][r + 1][g];
            float4 zh = As[sp][r + 1][g];
            float pw = (g > 0)      ? As[sc][r + 1][g - 1].w : INFINITY;
            float nx = (g < NG - 1) ? As[sc][r + 1][g + 1].x : INFINITY;
            float4 xl = make_float4(pw, c.x, c.y, c.z);
            float4 xr = make_float4(c.y, c.z, c.w, nx);
            float4 m = min4(c, xl);
            m = min4(m, xr);
            m = min4(m, yl);
            m = min4(m, yh);
            m = min4(m, zl);
            m = min4(m, zh);
            int gy = y0 - 1 + r;
            int gx0 = x0 - 4 + 4 * g;
            if (gy < 0 || gy >= NY || gx0 < 0 || gx0 >= NX) m = NINF4;
            dst[j] = m;
            if (wr && r >= 1 && r <= TY && g >= 1 && g <= NG - 2)
                *(float4*)(Ev + (size_t)z * ZS + gy * YS + gx0) = m;
        }
    };

    stageA(z0 - 2); stageA(z0 - 1); stageA(z0); stageA(z0 + 1);
    __syncthreads();
    eplane(z0 - 1);
    eplane(z0);
    __syncthreads();
    stageA(z0 + 2);
    __syncthreads();

    for (int z = z0; z < z1; ++z) {
        stageA(z + 3);
        eplane(z + 1);
        __syncthreads();
        {
            const float4* e0 = &Es[(z + 8) % 3][0][0];
            const float4* e1 = &Es[(z + 9) % 3][0][0];
            const float4* e2 = &Es[(z + 10) % 3][0][0];
            float4* mm = &Ms[0][0];
            for (int j = tid; j < EJOBS; j += 256)
                mm[j] = max4(max4(e0[j], e1[j]), e2[j]);
        }
        __syncthreads();
        if (tid < UJOBS) {
            int r = tid / (TX / 4);
            int gp = tid - r * (TX / 4);
            int g = gp + 1;
            float4 d = NINF4;
#pragma unroll
            for (int dy = 0; dy < 3; ++dy) {
                float a  = Ms[r + dy][g - 1].w;
                float4 b = Ms[r + dy][g];
                float c  = Ms[r + dy][g + 1].x;
                d = max4(d, win3max(a, b, c));
            }
            float4 av = As[(z + 8) & 3][r + 2][g];
            float4 delta = make_float4(fmaxf(av.x - d.x, 0.0f),
                                       fmaxf(av.y - d.y, 0.0f),
                                       fmaxf(av.z - d.z, 0.0f),
                                       fmaxf(av.w - d.w, 0.0f));
            size_t gi = (size_t)z * ZS + (size_t)(y0 + r) * YS + (x0 + gp * 4);
            float4* sp4 = (float4*)(Sv + gi);
            float4 s = *sp4;
            s.x += fmaxf(delta.x - s.x * delta.x, 0.0f);
            s.y += fmaxf(delta.y - s.y * delta.y, 0.0f);
            s.z += fmaxf(delta.z - s.z * delta.z, 0.0f);
            s.w += fmaxf(delta.w - s.w * delta.w, 0.0f);
            *sp4 = s;
        }
        __syncthreads();
    }
}

// ---------------- double-round kernel: 2 erosion rounds per launch ----------
// E1 = erode(A);  skel-update(A, E1);  E2 = erode(E1);  skel-update(E1, E2);
// writes E2 (next launch input) + skel.  Traffic per round is halved.
// Padding conventions: A/E1/E2 store +inf at out-of-volume cells (erode pad);
// the M-fills (dilate z-max) substitute -inf per-cell (dilate pad).
__global__ __launch_bounds__(256, 3) void fused2_kernel(const float* __restrict__ A,
                                                        float* __restrict__ E,
                                                        float* __restrict__ skel) {
    __shared__ float4 As[3][TY + 6][NGP];    /* halo 3 */
    __shared__ float4 E1s[3][TY + 4][NGP];   /* halo 2 */
    __shared__ float4 E2s[3][TY + 2][NGP];   /* halo 1 */
    __shared__ float4 M1s[TY + 2][NGP];
    __shared__ float4 M2s[TY + 2][NGP];

    const int tid = threadIdx.x;
    const int x0 = blockIdx.x * TX;
    const int y0 = blockIdx.y * TY;
    const int v  = blockIdx.z >> 2;
    const int z0 = (blockIdx.z & 3) * ZCH;
    const int z1 = z0 + ZCH;

    const float* Av = A + (size_t)v * VOL;
    float* Ev = E + (size_t)v * VOL;
    float* Sv = skel + (size_t)v * VOL;

    const float4 PINF4 = make_float4(INFINITY, INFINITY, INFINITY, INFINITY);
    const float4 NINF4 = make_float4(-INFINITY, -INFINITY, -INFINITY, -INFINITY);

    auto stageA = [&](int z) {
        int s = (z + 9) % 3;
        if (z < 0 || z >= NZ) {
            for (int j = tid; j < (TY + 6) * NG; j += 256) {
                int r = j / NG, g = j - r * NG;
                As[s][r][g] = PINF4;
            }
        } else {
            const float* P = Av + (size_t)z * ZS;
            for (int j = tid; j < (TY + 6) * NG; j += 256) {
                int r = j / NG, g = j - r * NG;
                int gy = y0 - 3 + r;
                int gx0 = x0 - 4 + 4 * g;
                float4 val = PINF4;
                if (gy >= 0 && gy < NY && gx0 >= 0 && gx0 < NX)
                    val = *(const float4*)(P + gy * YS + gx0);
                As[s][r][g] = val;
            }
        }
    };

    auto eplane1 = [&](int z) {           // E1(z) = erode(A)(z), halo 2
        if (z < 0 || z >= NZ) return;     // consumers gate out-of-range z
        const int sc = (z + 9) % 3;
        const int sm = (z + 8) % 3;
        const int sp = (z + 10) % 3;
        for (int j = tid; j < (TY + 4) * NG; j += 256) {
            int r = j / NG, g = j - r * NG;
            int gy = y0 - 2 + r;
            int gx0 = x0 - 4 + 4 * g;
            float4 m;
            if (gy < 0 || gy >= NY || gx0 < 0 || gx0 >= NX) {
                m = PINF4;
            } else {
                int ar = r + 1;
                float4 c  = As[sc][ar][g];
                float4 yl = As[sc][ar - 1][g];
                float4 yh = As[sc][ar + 1][g];
                float4 zl = As[sm][ar][g];
                float4 zh = As[sp][ar][g];
                float pw = (g > 0)      ? As[sc][ar][g - 1].w : INFINITY;
                float nx = (g < NG - 1) ? As[sc][ar][g + 1].x : INFINITY;
                m = min4(c, make_float4(pw, c.x, c.y, c.z));
                m = min4(m, make_float4(c.y, c.z, c.w, nx));
                m = min4(m, yl); m = min4(m, yh);
                m = min4(m, zl); m = min4(m, zh);
            }
            E1s[sc][r][g] = m;
        }
    };

    auto eplane2 = [&](int z, bool wr) {  // E2(z) = erode(E1)(z), halo 1
        if (z < 0 || z >= NZ) return;
        const int sc = (z + 9) % 3;
        const int sm = (z + 8) % 3;
        const int sp = (z + 10) % 3;
        const bool hm = (z - 1 >= 0), hp = (z + 1 < NZ);
        for (int j = tid; j < (TY + 2) * NG; j += 256) {
            int r = j / NG, g = j - r * NG;
            int gy = y0 - 1 + r;
            int gx0 = x0 - 4 + 4 * g;
            float4 m;
            if (gy < 0 || gy >= NY || gx0 < 0 || gx0 >= NX) {
                m = PINF4;
            } else {
                int er = r + 1;
                float4 c  = E1s[sc][er][g];
                float4 yl = E1s[sc][er - 1][g];
                float4 yh = E1s[sc][er + 1][g];
                float4 zl = hm ? E1s[sm][er][g] : PINF4;
                float4 zh = hp ? E1s[sp][er][g] : PINF4;
                float pw = (g > 0)      ? E1s[sc][er][g - 1].w : INFINITY;
                float nx = (g < NG - 1) ? E1s[sc][er][g + 1].x : INFINITY;
                m = min4(c, make_float4(pw, c.x, c.y, c.z));
                m = min4(m, make_float4(c.y, c.z, c.w, nx));
                m = min4(m, yl); m = min4(m, yh);
                m = min4(m, zl); m = min4(m, zh);
                if (wr && r >= 1 && r <= TY && g >= 1 && g <= NG - 2)
                    *(float4*)(Ev + (size_t)z * ZS + gy * YS + gx0) = m;
            }
            E2s[sc][r][g] = m;
        }
    };

    auto m1fill = [&](int z) {            // M1(z) = zmax E1(z-1..z+1), dilate pad
        if (z < 0 || z >= NZ) return;
        const bool hm = (z - 1 >= 0), hp = (z + 1 < NZ);
        const int s0 = (z + 8) % 3, s1 = (z + 9) % 3, s2 = (z + 10) % 3;
        for (int j = tid; j < (TY + 2) * NG; j += 256) {
            int r = j / NG, g = j - r * NG;
            int gy = y0 - 1 + r;
            int gx0 = x0 - 4 + 4 * g;
            float4 m = NINF4;
            if (gy >= 0 && gy < NY && gx0 >= 0 && gx0 < NX) {
                int er = r + 1;
                m = E1s[s1][er][g];
                if (hm) m = max4(m, E1s[s0][er][g]);
                if (hp) m = max4(m, E1s[s2][er][g]);
            }
            M1s[r][g] = m;
        }
    };

    auto m2fill = [&](int z) {            // M2(z) = zmax E2(z-1..z+1), dilate pad
        const bool h0 = (z - 1 >= 0) && (z - 1 < NZ);
        const bool h1 = (z >= 0) && (z < NZ);
        const bool h2 = (z + 1 >= 0) && (z + 1 < NZ);
        const int s0 = (z + 8) % 3, s1 = (z + 9) % 3, s2 = (z + 10) % 3;
        for (int j = tid; j < (TY + 2) * NG; j += 256) {
            int r = j / NG, g = j - r * NG;
            int gy = y0 - 1 + r;
            int gx0 = x0 - 4 + 4 * g;
            float4 m = NINF4;
            if (gy >= 0 && gy < NY && gx0 >= 0 && gx0 < NX) {
                if (h1) m = max4(m, E2s[s1][r][g]);
                if (h0) m = max4(m, E2s[s0][r][g]);
                if (h2) m = max4(m, E2s[s2][r][g]);
            }
            M2s[r][g] = m;
        }
    };

    const int r_u = tid / (TX / 4);
    const int gp  = tid - r_u * (TX / 4);
    const int gu  = gp + 1;
    float4 sprev = make_float4(0.f, 0.f, 0.f, 0.f);
    float4 scur  = sprev;

    // ---- prologue: A(z0-3..z0+1), E1(z0-2..z0), E2(z0-1) ----
    stageA(z0 - 3); stageA(z0 - 2); stageA(z0 - 1);
    __syncthreads();
    eplane1(z0 - 2);
    __syncthreads();
    stageA(z0);
    __syncthreads();
    eplane1(z0 - 1);
    __syncthreads();
    stageA(z0 + 1);
    __syncthreads();
    eplane1(z0);
    __syncthreads();
    eplane2(z0 - 1, false);
    __syncthreads();

    // ---- body: z = z0..z1 inclusive ----
    for (int z = z0; z <= z1; ++z) {
        // P1: prefetch A(z+2)
        stageA(z + 2);
        __syncthreads();
        // P2: E1(z+1)
        eplane1(z + 1);
        __syncthreads();
        // P3: E2(z) (+global write), M1(z)
        eplane2(z, z < z1);
        if (z < z1) m1fill(z);
        __syncthreads();
        // P4: update1(z) -> scur (registers); M2(z-1)
        if (z < z1 && tid < UJOBS) {
            float4 d = NINF4;
#pragma unroll
            for (int dy = 0; dy < 3; ++dy) {
                int rm = r_u + dy;
                d = max4(d, win3max(M1s[rm][gu - 1].w, M1s[rm][gu], M1s[rm][gu + 1].x));
            }
            float4 a = As[(z + 9) % 3][r_u + 3][gu];
            size_t gi = (size_t)z * ZS + (size_t)(y0 + r_u) * YS + (x0 + 4 * gp);
            float4 s = *(const float4*)(Sv + gi);
            float dd;
            dd = fmaxf(a.x - d.x, 0.f); s.x += fmaxf(dd - s.x * dd, 0.f);
            dd = fmaxf(a.y - d.y, 0.f); s.y += fmaxf(dd - s.y * dd, 0.f);
            dd = fmaxf(a.z - d.z, 0.f); s.z += fmaxf(dd - s.z * dd, 0.f);
            dd = fmaxf(a.w - d.w, 0.f); s.w += fmaxf(dd - s.w * dd, 0.f);
            scur = s;
        }
        m2fill(z - 1);
        __syncthreads();
        // P5: update2(z-1) using sprev; write skel(z-1)
        if (z > z0 && tid < UJOBS) {
            float4 d = NINF4;
#pragma unroll
            for (int dy = 0; dy < 3; ++dy) {
                int rm = r_u + dy;
                d = max4(d, win3max(M2s[rm][gu - 1].w, M2s[rm][gu], M2s[rm][gu + 1].x));
            }
            float4 a = E1s[(z + 8) % 3][r_u + 2][gu];
            float4 s = sprev;
            float dd;
            dd = fmaxf(a.x - d.x, 0.f); s.x += fmaxf(dd - s.x * dd, 0.f);
            dd = fmaxf(a.y - d.y, 0.f); s.y += fmaxf(dd - s.y * dd, 0.f);
            dd = fmaxf(a.z - d.z, 0.f); s.z += fmaxf(dd - s.z * dd, 0.f);
            dd = fmaxf(a.w - d.w, 0.f); s.w += fmaxf(dd - s.w * dd, 0.f);
            size_t gi = (size_t)(z - 1) * ZS + (size_t)(y0 + r_u) * YS + (x0 + 4 * gp);
            *(float4*)(Sv + gi) = s;
        }
        sprev = scur;
    }
}

__global__ void reduce_kernel(const float* __restrict__ skel,
                              const float* __restrict__ pred,
                              const float* __restrict__ target,
                              double* __restrict__ sums) {
    double acc[4] = {0.0, 0.0, 0.0, 0.0};
    const int stride = gridDim.x * blockDim.x;
    const int t0 = blockIdx.x * blockDim.x + threadIdx.x;
    for (int v = 0; v < NV; ++v) {
        const float* base = (v < 2) ? target : pred;
        const float4* in4 = (const float4*)(base + (size_t)((v & 1) * 2 + 1) * VOL);
        const float4* sk4 = (const float4*)(skel + (size_t)v * VOL);
        float fd = 0.f, fs = 0.f;
        for (int p = t0; p < VOL4; p += stride) {
            float4 s = sk4[p], o = in4[p];
            fd += s.x * o.x + s.y * o.y + s.z * o.z + s.w * o.w;
            fs += s.x + s.y + s.z + s.w;
        }
        if (v < 2) { acc[0] += (double)fd; acc[1] += (double)fs; }
        else       { acc[2] += (double)fd; acc[3] += (double)fs; }
    }
#pragma unroll
    for (int off = 32; off > 0; off >>= 1) {
#pragma unroll
        for (int k = 0; k < 4; ++k) acc[k] += __shfl_down(acc[k], off, 64);
    }
    __shared__ double sm[4][4];
    int lane = threadIdx.x & 63;
    int wid = threadIdx.x >> 6;
    if (lane == 0) {
#pragma unroll
        for (int k = 0; k < 4; ++k) sm[wid][k] = acc[k];
    }
    __syncthreads();
    if (threadIdx.x == 0) {
#pragma unroll
        for (int k = 0; k < 4; ++k) {
            double t = sm[0][k] + sm[1][k] + sm[2][k] + sm[3][k];
            atomicAdd(&sums[k], t);
        }
    }
}

__global__ void final_kernel(const double* __restrict__ sums,
                             float* __restrict__ out) {
    if (threadIdx.x == 0 && blockIdx.x == 0) {
        const double SM = 1e-5;
        double tprec = (sums[0] + SM) / (sums[1] + SM);
        double tsens = (sums[2] + SM) / (sums[3] + SM);
        double cl = 2.0 * tprec * tsens / (tprec + tsens + SM);
        out[0] = (float)(1.0 - cl);
    }
}

extern "C" void kernel_launch(void* const* d_in, const int* in_sizes, int n_in,
                              void* d_out, int out_size, void* d_ws, size_t ws_size,
                              hipStream_t stream) {
    const float* pred = (const float*)d_in[0];
    const float* target = (const float*)d_in[1];
    float* out = (float*)d_out;

    float* cur = (float*)d_ws;
    float* ero = cur + NTOT;
    float* skel = ero + NTOT;
    double* sums = (double*)(skel + NTOT);

    hipMemsetAsync(skel, 0, (size_t)NTOT * sizeof(float), stream);
    hipMemsetAsync(sums, 0, 4 * sizeof(double), stream);

    extract_kernel<<<NTOT4 / 256, 256, 0, stream>>>(pred, target, cur);

    dim3 fgrid(NX / TX, NY / TY, NV * 4);   // 4 x 12 x 16 = 768 blocks (3/CU)

    // round 0 (single), then 25 double-round launches: 1 + 25*2 = 51 rounds
    fused_kernel<<<fgrid, 256, 0, stream>>>(cur, ero, skel);
    float* Abuf = ero;
    float* Ebuf = cur;
    for (int j = 0; j < 25; ++j) {
        fused2_kernel<<<fgrid, 256, 0, stream>>>(Abuf, Ebuf, skel);
        float* tmp = Abuf; Abuf = Ebuf; Ebuf = tmp;
    }

    reduce_kernel<<<2048, 256, 0, stream>>>(skel, pred, target, sums);
    final_kernel<<<1, 64, 0, stream>>>(sums, out);
}